// Round 5
// baseline (562.792 us; speedup 1.0000x reference)
//
#include <hip/hip_runtime.h>
#include <stdint.h>

#define N 8192
#define G 7
#define T 512
#define NW 8          // waves per block
typedef uint32_t u32;
typedef uint16_t u16;

// Map float bits -> uint32 such that ascending uint order == DESCENDING float
// order, XLA total-order semantics. Stable LSD radix handles index tie-break.
__device__ __forceinline__ u32 enc_desc(float x) {
    u32 u = __float_as_uint(x);
    return (u & 0x80000000u) ? u : (~u & 0x7FFFFFFFu);
}
__device__ __forceinline__ float dec_desc(u32 k) {
    u32 u = (k & 0x80000000u) ? k : (~k & 0x7FFFFFFFu);
    return __uint_as_float(u);
}

// LDS budget: 32768(val) + 16384(idx) + 4096(wcnt u16) + 512(dsum u16) + 16(wsum)
// = 53776 B -> 54272 alloc (512B gran); x3 = 162816 <= 163840 -> 3 blocks/CU.
__global__ __launch_bounds__(T, 6) void portfolio_radix_kernel(
    const float* __restrict__ x,
    float* __restrict__ bc,        // [B, N] float32
    float* __restrict__ idx_out)   // [B, N] indices as float32
{
    __shared__ u32 val_s[N];          // 32 KiB  sort keys (enc values)
    __shared__ u16 idx_s[N];          // 16 KiB  payload indices (<8192)
    __shared__ u16 wcnt[NW * 256];    // 4 KiB   per-wave digit counters (u16)
    __shared__ u16 dsum[256];         // 512 B   exclusive digit bases (in-chunk)
    __shared__ u32 wsum[4];           // chunk totals for 256-wide scan

    const int t    = threadIdx.x;
    const int w    = t >> 6;          // wave 0..7
    const int lane = t & 63;
    const int row  = blockIdx.x;
    const float* xr  = x + (size_t)row * N;
    float* bcr = bc + (size_t)row * N;
    float* ixr = idx_out + (size_t)row * N;

    u32* wcnt32 = (u32*)wcnt;         // atomic/zeroing view (1 word = 2 digits)

    // Element ownership e = 1024*w + 64*j + lane: ownership order (w, j, lane)
    // == index order, matching rank composition wave-base + program-order +
    // ascending-lane atomic serialization (tie-stability validated round 3).
    // Plain u32 register arrays (round-3 dataflow: 48 live regs, no spill).
    u32 hi[16];                        // sort key per element
    u32 ii[16];                        // payload index per element
    u32 rnk[16];                       // in-wave rank per element
#pragma unroll
    for (int j = 0; j < 16; ++j) {
        int e = (w << 10) | (j << 6) | lane;
        hi[j] = enc_desc(xr[e]);
        ii[j] = (u32)e;
    }
    // zero own wave's counter row (128 words); phase A touches only this row
    // from this wave -> no barrier needed before pass 0.
    wcnt32[(w << 7) + lane] = 0;
    wcnt32[(w << 7) + 64 + lane] = 0;

    for (int p = 0; p < 4; ++p) {
        const int shift = 8 * p;

        // ---- phase A: stable in-wave rank via ds_add_rtn_u32 on u16 halves.
        // Word (w*128 + d/2), half (d&1); per-wave counts <= 1024 so halves
        // never carry. Ascending-lane same-address serialization (validated
        // round 3) preserves per-digit stability.
#pragma unroll
        for (int j = 0; j < 16; ++j) {
            u32 d   = (hi[j] >> shift) & 255u;
            u32 sh  = (d & 1u) << 4;
            u32 ret = atomicAdd(&wcnt32[(w << 7) + (d >> 1)], 1u << sh);
            rnk[j]  = (ret >> sh) & 0xFFFFu;
        }
        __syncthreads();                       // B1: all counts visible

        // ---- scan: threads 0..255 own one digit each (u16 element access;
        // ds_write_b16 byte-enables handle shared words).
        if (t < 256) {
            u32 run = 0;
#pragma unroll
            for (int ww = 0; ww < NW; ++ww) {  // serial over waves: exclusive
                u32 c = (u32)wcnt[(ww << 8) | t];
                wcnt[(ww << 8) | t] = (u16)run;
                run += c;
            }
            u32 v = run;                        // digit total; 64-wide scan
#pragma unroll
            for (int off = 1; off < 64; off <<= 1) {
                u32 u = __shfl_up(v, off, 64);
                if (lane >= off) v += u;
            }
            if (lane == 63) wsum[w] = v;        // chunk total (w = 0..3 here)
            dsum[t] = (u16)(v - run);           // exclusive within chunk
        }
        __syncthreads();                       // B2: bases/dsum/wsum visible

        // ---- fold own row + scatter + re-zero: single phase, wave-private.
        {
            u32 a0 = wsum[0], a1 = wsum[1], a2 = wsum[2];
#pragma unroll
            for (int i = 0; i < 4; ++i) {       // chunk index i (compile-time)
                int d = lane + (i << 6);
                u32 addv = (i > 0 ? a0 : 0u) + (i > 1 ? a1 : 0u) + (i > 2 ? a2 : 0u);
                wcnt[(w << 8) + d] = (u16)((u32)wcnt[(w << 8) + d] + (u32)dsum[d] + addv);
            }
        }
#pragma unroll
        for (int j = 0; j < 16; ++j) {
            u32 d   = (hi[j] >> shift) & 255u;
            u32 pos = rnk[j] + (u32)wcnt[(w << 8) + d];
            // last pass: only head/tail G values are ever read back
            if (p < 3 || pos < G || pos >= N - G) val_s[pos] = hi[j];
            idx_s[pos] = (u16)ii[j];
        }
        // compiler fence: u32 zero-stores below must not hoist above the u16
        // base-reads in the scatter loop (mixed-width aliasing).
        asm volatile("" ::: "memory");
        wcnt32[(w << 7) + lane] = 0;
        wcnt32[(w << 7) + 64 + lane] = 0;
        __syncthreads();                       // B3: scatter + re-zero done

        if (p < 3) {                           // gather; next phase A follows
            // with no barrier (disjoint arrays: val/idx vs wcnt)
#pragma unroll
            for (int j = 0; j < 16; ++j) {
                int e = (w << 10) | (j << 6) | lane;
                hi[j] = val_s[e];
                ii[j] = (u32)idx_s[e];
            }
        }
    }

    // ---- outputs (round-3 epilogue): idx_s holds final order ----
#pragma unroll
    for (int j = 0; j < 16; ++j) {
        int e = (w << 10) | (j << 6) | lane;    // per-slot coalesced stores
        ixr[e] = (float)idx_s[e];
        bcr[e] = 0.0f;
    }
    // winner: threads 0..6 redundantly compute softmax(top-7), write own slot
    // (overwrites this thread's own j=0 zero-write: same thread, program order).
    if (t < G) {
        float s[G], ex[G], sum = 0.f;
#pragma unroll
        for (int g = 0; g < G; ++g) s[g] = dec_desc(val_s[g]);
        float m0 = s[0];                        // max (descending values)
#pragma unroll
        for (int g = 0; g < G; ++g) { ex[g] = expf(s[g] - m0); sum += ex[g]; }
        bcr[t] = ex[t] / sum;
    }
    // loser: threads 505..511 -> positions N-G..N-1.
    // -softmax(1 - bottom) == -softmax(-bottom) (shift invariance)
    if (t >= T - G) {
        float s[G], ex[G], sum = 0.f;
#pragma unroll
        for (int g = 0; g < G; ++g) s[g] = dec_desc(val_s[N - G + g]);
        float m0 = -s[G - 1];                   // max of -s (s descending)
#pragma unroll
        for (int g = 0; g < G; ++g) { ex[g] = expf(-s[g] - m0); sum += ex[g]; }
        bcr[(N - T) + t] = -ex[t - (T - G)] / sum;
    }
}

extern "C" void kernel_launch(void* const* d_in, const int* in_sizes, int n_in,
                              void* d_out, int out_size, void* d_ws, size_t ws_size,
                              hipStream_t stream) {
    const float* x = (const float*)d_in[0];
    float* out = (float*)d_out;
    const int B = in_sizes[0] / N;               // 4096
    float* bc  = out;                             // output 0: [B, N]
    float* idx = out + (size_t)B * N;             // output 1: [B, N] (as float32)
    portfolio_radix_kernel<<<B, T, 0, stream>>>(x, bc, idx);
}

// Round 6
// 460.697 us; speedup vs baseline: 1.2216x; 1.2216x over previous
//
#include <hip/hip_runtime.h>
#include <stdint.h>

#define N 8192
#define G 7
#define T 512
#define NW 8          // waves per block
typedef uint32_t u32;
typedef uint16_t u16;

// Map float bits -> uint32 such that ascending uint order == DESCENDING float
// order, XLA total-order semantics. Stable LSD radix handles index tie-break.
__device__ __forceinline__ u32 enc_desc(float x) {
    u32 u = __float_as_uint(x);
    return (u & 0x80000000u) ? u : (~u & 0x7FFFFFFFu);
}
__device__ __forceinline__ float dec_desc(u32 k) {
    u32 u = (k & 0x80000000u) ? k : (~k & 0x7FFFFFFFu);
    return __uint_as_float(u);
}

// LDS budget: 32768(val) + 16384(idx) + 4096(wcnt u16) + 512(dsum u16) + 16(wsum)
// = 53776 B -> 54272 alloc (512B gran); x3 = 162816 <= 163840 -> 3 blocks/CU.
// NOTE: no min-occupancy arg in __launch_bounds__ — rounds 4/5 proved that
// `(T, 6)` pins the allocator at 40 VGPR and spills ~280 MB of scratch traffic.
// LDS already caps residency at 3 blocks/CU; 52-64 VGPR allows 8 waves/SIMD.
__global__ __launch_bounds__(T) void portfolio_radix_kernel(
    const float* __restrict__ x,
    float* __restrict__ bc,        // [B, N] float32
    float* __restrict__ idx_out)   // [B, N] indices as float32
{
    __shared__ u32 val_s[N];          // 32 KiB  sort keys (enc values)
    __shared__ u16 idx_s[N];          // 16 KiB  payload indices (<8192)
    __shared__ u16 wcnt[NW * 256];    // 4 KiB   per-wave digit counters (u16)
    __shared__ u16 dsum[256];         // 512 B   exclusive digit bases (in-chunk)
    __shared__ u32 wsum[4];           // chunk totals for 256-wide scan

    const int t    = threadIdx.x;
    const int w    = t >> 6;          // wave 0..7
    const int lane = t & 63;
    const int row  = blockIdx.x;
    const float* xr  = x + (size_t)row * N;
    float* bcr = bc + (size_t)row * N;
    float* ixr = idx_out + (size_t)row * N;

    u32* wcnt32 = (u32*)wcnt;         // atomic/zeroing view (1 word = 2 digits)

    // Element ownership e = 1024*w + 64*j + lane: ownership order (w, j, lane)
    // == index order, matching rank composition wave-base + program-order +
    // ascending-lane atomic serialization (tie-stability validated round 3).
    // Plain u32 register arrays (round-3 dataflow: 48 live regs, no spill).
    u32 hi[16];                        // sort key per element
    u32 ii[16];                        // payload index per element
    u32 rnk[16];                       // in-wave rank per element
#pragma unroll
    for (int j = 0; j < 16; ++j) {
        int e = (w << 10) | (j << 6) | lane;
        hi[j] = enc_desc(xr[e]);
        ii[j] = (u32)e;
    }
    // zero own wave's counter row (128 words); phase A touches only this row
    // from this wave -> no barrier needed before pass 0.
    wcnt32[(w << 7) + lane] = 0;
    wcnt32[(w << 7) + 64 + lane] = 0;

    for (int p = 0; p < 4; ++p) {
        const int shift = 8 * p;

        // ---- phase A: stable in-wave rank via ds_add_rtn_u32 on u16 halves.
        // Word (w*128 + d/2), half (d&1); per-wave counts <= 1024 so halves
        // never carry. Ascending-lane same-address serialization (validated
        // round 3) preserves per-digit stability.
#pragma unroll
        for (int j = 0; j < 16; ++j) {
            u32 d   = (hi[j] >> shift) & 255u;
            u32 sh  = (d & 1u) << 4;
            u32 ret = atomicAdd(&wcnt32[(w << 7) + (d >> 1)], 1u << sh);
            rnk[j]  = (ret >> sh) & 0xFFFFu;
        }
        __syncthreads();                       // B1: all counts visible

        // ---- scan: threads 0..255 own one digit each (u16 element access;
        // ds_write_b16 byte-enables handle shared words).
        if (t < 256) {
            u32 run = 0;
#pragma unroll
            for (int ww = 0; ww < NW; ++ww) {  // serial over waves: exclusive
                u32 c = (u32)wcnt[(ww << 8) | t];
                wcnt[(ww << 8) | t] = (u16)run;
                run += c;
            }
            u32 v = run;                        // digit total; 64-wide scan
#pragma unroll
            for (int off = 1; off < 64; off <<= 1) {
                u32 u = __shfl_up(v, off, 64);
                if (lane >= off) v += u;
            }
            if (lane == 63) wsum[w] = v;        // chunk total (w = 0..3 here)
            dsum[t] = (u16)(v - run);           // exclusive within chunk
        }
        __syncthreads();                       // B2: bases/dsum/wsum visible

        // ---- fold own row + scatter + re-zero: single phase, wave-private.
        {
            u32 a0 = wsum[0], a1 = wsum[1], a2 = wsum[2];
#pragma unroll
            for (int i = 0; i < 4; ++i) {       // chunk index i (compile-time)
                int d = lane + (i << 6);
                u32 addv = (i > 0 ? a0 : 0u) + (i > 1 ? a1 : 0u) + (i > 2 ? a2 : 0u);
                wcnt[(w << 8) + d] = (u16)((u32)wcnt[(w << 8) + d] + (u32)dsum[d] + addv);
            }
        }
#pragma unroll
        for (int j = 0; j < 16; ++j) {
            u32 d   = (hi[j] >> shift) & 255u;
            u32 pos = rnk[j] + (u32)wcnt[(w << 8) + d];
            // last pass: only head/tail G values are ever read back
            if (p < 3 || pos < G || pos >= N - G) val_s[pos] = hi[j];
            idx_s[pos] = (u16)ii[j];
        }
        // compiler fence: u32 zero-stores below must not hoist above the u16
        // base-reads in the scatter loop (mixed-width aliasing).
        asm volatile("" ::: "memory");
        wcnt32[(w << 7) + lane] = 0;
        wcnt32[(w << 7) + 64 + lane] = 0;
        __syncthreads();                       // B3: scatter + re-zero done

        if (p < 3) {                           // gather; next phase A follows
            // with no barrier (disjoint arrays: val/idx vs wcnt)
#pragma unroll
            for (int j = 0; j < 16; ++j) {
                int e = (w << 10) | (j << 6) | lane;
                hi[j] = val_s[e];
                ii[j] = (u32)idx_s[e];
            }
        }
    }

    // ---- outputs (round-3 epilogue): idx_s holds final order ----
#pragma unroll
    for (int j = 0; j < 16; ++j) {
        int e = (w << 10) | (j << 6) | lane;    // per-slot coalesced stores
        ixr[e] = (float)idx_s[e];
        bcr[e] = 0.0f;
    }
    // winner: threads 0..6 redundantly compute softmax(top-7), write own slot
    // (overwrites this thread's own j=0 zero-write: same thread, program order).
    if (t < G) {
        float s[G], ex[G], sum = 0.f;
#pragma unroll
        for (int g = 0; g < G; ++g) s[g] = dec_desc(val_s[g]);
        float m0 = s[0];                        // max (descending values)
#pragma unroll
        for (int g = 0; g < G; ++g) { ex[g] = expf(s[g] - m0); sum += ex[g]; }
        bcr[t] = ex[t] / sum;
    }
    // loser: threads 505..511 -> positions N-G..N-1.
    // -softmax(1 - bottom) == -softmax(-bottom) (shift invariance)
    if (t >= T - G) {
        float s[G], ex[G], sum = 0.f;
#pragma unroll
        for (int g = 0; g < G; ++g) s[g] = dec_desc(val_s[N - G + g]);
        float m0 = -s[G - 1];                   // max of -s (s descending)
#pragma unroll
        for (int g = 0; g < G; ++g) { ex[g] = expf(-s[g] - m0); sum += ex[g]; }
        bcr[(N - T) + t] = -ex[t - (T - G)] / sum;
    }
}

extern "C" void kernel_launch(void* const* d_in, const int* in_sizes, int n_in,
                              void* d_out, int out_size, void* d_ws, size_t ws_size,
                              hipStream_t stream) {
    const float* x = (const float*)d_in[0];
    float* out = (float*)d_out;
    const int B = in_sizes[0] / N;               // 4096
    float* bc  = out;                             // output 0: [B, N]
    float* idx = out + (size_t)B * N;             // output 1: [B, N] (as float32)
    portfolio_radix_kernel<<<B, T, 0, stream>>>(x, bc, idx);
}

// Round 7
// 442.845 us; speedup vs baseline: 1.2709x; 1.0403x over previous
//
#include <hip/hip_runtime.h>
#include <stdint.h>

#define N 8192
#define G 7
#define T 512
#define NW 8          // waves per block
typedef uint32_t u32;
typedef uint16_t u16;

// Map float bits -> uint32 such that ascending uint order == DESCENDING float
// order, XLA total-order semantics. Stable LSD radix handles index tie-break.
__device__ __forceinline__ u32 enc_desc(float x) {
    u32 u = __float_as_uint(x);
    return (u & 0x80000000u) ? u : (~u & 0x7FFFFFFFu);
}
__device__ __forceinline__ float dec_desc(u32 k) {
    u32 u = (k & 0x80000000u) ? k : (~k & 0x7FFFFFFFu);
    return __uint_as_float(u);
}

// Digit d (0..255) -> u16 slot inside a 128-word per-wave counter row.
// Pairing d <-> d^0xAB (bit7 differs): word = (d&127) ^ ((d>>7)*0x2B),
// half = d>>7. Chosen so the 12 hot pass-3 digits (sign/exponent bytes of
// N(0,1) data: 0x3D..0x42 and 0xBD..0xC2) land in 12 DISTINCT words ->
// no doubled atomic serialization (round-6's even/odd split shared words).
__device__ __forceinline__ u32 dig_word(u32 d) { return (d & 127u) ^ ((d >> 7) * 0x2Bu); }
__device__ __forceinline__ u32 dig_col16(u32 d) { return (dig_word(d) << 1) | (d >> 7); }

// LDS: 32768(val) + 16384(idx) + 4096(wcnt) + 16(wsum) = 53264 B
// -> alloc 53760 (512B gran); x3 = 161280 <= 163840 with 2.5 KiB headroom.
// This is the honest 3-blocks/CU retest (round 6's 54272 left only 1 KiB).
// NOTE: no min-occupancy arg in __launch_bounds__ — rounds 4/5 proved (T,6)
// pins the allocator at 40 VGPR and spills ~280 MB of scratch traffic.
__global__ __launch_bounds__(T) void portfolio_radix_kernel(
    const float* __restrict__ x,
    float* __restrict__ bc,        // [B, N] float32
    float* __restrict__ idx_out)   // [B, N] indices as float32
{
    __shared__ u32 val_s[N];          // 32 KiB  sort keys (enc values)
    __shared__ u16 idx_s[N];          // 16 KiB  payload indices (<8192)
    __shared__ u32 wcnt32[NW * 128];  // 4 KiB   per-wave digit counters (u16 pairs)
    __shared__ u32 wsum[4];           // chunk totals for the 256-wide scan

    const int t    = threadIdx.x;
    const int w    = t >> 6;          // wave 0..7
    const int lane = t & 63;
    const int row  = blockIdx.x;
    const float* xr  = x + (size_t)row * N;
    float* bcr = bc + (size_t)row * N;
    float* ixr = idx_out + (size_t)row * N;

    u16* wcnt16 = (u16*)wcnt32;       // element view for scan/fold/scatter reads

    // Element ownership e = 1024*w + 64*j + lane: ownership order (w, j, lane)
    // == index order, matching rank composition wave-base + program-order +
    // ascending-lane atomic serialization (tie-stability validated round 3).
    u32 hi[16];                        // sort key per element
    u32 ii[16];                        // payload index per element
    u32 rnk[16];                       // in-wave rank per element
#pragma unroll
    for (int j = 0; j < 16; ++j) {
        int e = (w << 10) | (j << 6) | lane;
        hi[j] = enc_desc(xr[e]);
        ii[j] = (u32)e;
        // bc is zero except head/tail G; stream the zeros now so the 134 MB
        // of global writes overlap the whole sort. Head/tail slots are left
        // for the epilogue softmax threads (no cross-thread same-addr WAW).
        if (e >= G && e < N - G) bcr[e] = 0.0f;
    }
    // zero own wave's counter row (128 words); phase A touches only this row
    // from this wave -> no barrier needed before pass 0.
    wcnt32[(w << 7) + lane] = 0;
    wcnt32[(w << 7) + 64 + lane] = 0;

    for (int p = 0; p < 4; ++p) {
        const int shift = 8 * p;

        // ---- phase A: stable in-wave rank via ds_add_rtn_u32 on u16 halves.
        // Per-wave counts <= 1024 -> halves never carry. Ascending-lane
        // same-address serialization (validated round 3) preserves stability.
#pragma unroll
        for (int j = 0; j < 16; ++j) {
            u32 d   = (hi[j] >> shift) & 255u;
            u32 sh  = (d >> 7) << 4;
            u32 ret = atomicAdd(&wcnt32[(w << 7) + dig_word(d)], 1u << sh);
            rnk[j]  = (ret >> sh) & 0xFFFFu;
        }
        __syncthreads();                       // B1: all counts visible

        // ---- scan part 1: threads 0..255 own one digit each. Serial over
        // waves (exclusive per-wave bases written back), then 64-wide shuffle
        // scan per chunk; chunk totals to wsum.
        u32 vtot = 0, runv = 0;
        if (t < 256) {
            const int col = (int)dig_col16((u32)t);
            u32 run = 0;
#pragma unroll
            for (int ww = 0; ww < NW; ++ww) {
                u32 c = (u32)wcnt16[(ww << 8) + col];
                wcnt16[(ww << 8) + col] = (u16)run;
                run += c;
            }
            u32 v = run;                        // digit total; 64-wide scan
#pragma unroll
            for (int off = 1; off < 64; off <<= 1) {
                u32 u = __shfl_up(v, off, 64);
                if (lane >= off) v += u;
            }
            if (lane == 63) wsum[w] = v;        // chunk total (w = 0..3 here)
            vtot = v; runv = run;
        }
        __syncthreads();                       // B2: wsum visible

        // ---- scan part 2 (dsum-free): scan threads fold the GLOBAL digit
        // base directly into all 8 per-wave rows (each digit column is owned
        // by exactly one scan thread -> race-free u16 RMW).
        if (t < 256) {
            u32 dbase = vtot - runv;            // exclusive within chunk
            if (w > 0) dbase += wsum[0];
            if (w > 1) dbase += wsum[1];
            if (w > 2) dbase += wsum[2];
            const int col = (int)dig_col16((u32)t);
#pragma unroll
            for (int ww = 0; ww < NW; ++ww)
                wcnt16[(ww << 8) + col] = (u16)((u32)wcnt16[(ww << 8) + col] + dbase);
        }
        __syncthreads();                       // B3: bases final

        // ---- scatter + re-zero own row (wave-private, round-6-proven) ----
#pragma unroll
        for (int j = 0; j < 16; ++j) {
            u32 d   = (hi[j] >> shift) & 255u;
            u32 pos = rnk[j] + (u32)wcnt16[(w << 8) + dig_col16(d)];
            // last pass: only head/tail G values are ever read back
            if (p < 3 || pos < G || pos >= N - G) val_s[pos] = hi[j];
            idx_s[pos] = (u16)ii[j];
        }
        // compiler fence: u32 zero-stores below must not hoist above the u16
        // base-reads in the scatter loop (mixed-width aliasing).
        asm volatile("" ::: "memory");
        wcnt32[(w << 7) + lane] = 0;
        wcnt32[(w << 7) + 64 + lane] = 0;
        __syncthreads();                       // B4: scatter + re-zero done

        if (p < 3) {                           // gather; next phase A follows
            // with no barrier (disjoint arrays: val/idx vs wcnt)
#pragma unroll
            for (int j = 0; j < 16; ++j) {
                int e = (w << 10) | (j << 6) | lane;
                hi[j] = val_s[e];
                ii[j] = (u32)idx_s[e];
            }
        }
    }

    // ---- outputs: idx_s holds final descending order's original indices ----
#pragma unroll
    for (int j = 0; j < 16; ++j) {
        int e = (w << 10) | (j << 6) | lane;    // coalesced stores
        ixr[e] = (float)idx_s[e];
    }
    // winner: threads 0..6 redundantly compute softmax(top-7), write own slot
    if (t < G) {
        float s[G], ex[G], sum = 0.f;
#pragma unroll
        for (int g = 0; g < G; ++g) s[g] = dec_desc(val_s[g]);
        float m0 = s[0];                        // max (descending values)
#pragma unroll
        for (int g = 0; g < G; ++g) { ex[g] = expf(s[g] - m0); sum += ex[g]; }
        bcr[t] = ex[t] / sum;
    }
    // loser: threads 505..511 -> positions N-G..N-1.
    // -softmax(1 - bottom) == -softmax(-bottom) (shift invariance)
    if (t >= T - G) {
        float s[G], ex[G], sum = 0.f;
#pragma unroll
        for (int g = 0; g < G; ++g) s[g] = dec_desc(val_s[N - G + g]);
        float m0 = -s[G - 1];                   // max of -s (s descending)
#pragma unroll
        for (int g = 0; g < G; ++g) { ex[g] = expf(-s[g] - m0); sum += ex[g]; }
        bcr[(N - T) + t] = -ex[t - (T - G)] / sum;
    }
}

extern "C" void kernel_launch(void* const* d_in, const int* in_sizes, int n_in,
                              void* d_out, int out_size, void* d_ws, size_t ws_size,
                              hipStream_t stream) {
    const float* x = (const float*)d_in[0];
    float* out = (float*)d_out;
    const int B = in_sizes[0] / N;               // 4096
    float* bc  = out;                             // output 0: [B, N]
    float* idx = out + (size_t)B * N;             // output 1: [B, N] (as float32)
    portfolio_radix_kernel<<<B, T, 0, stream>>>(x, bc, idx);
}